// Round 1
// baseline (4786.415 us; speedup 1.0000x reference)
//
#include <hip/hip_runtime.h>
#include <hip/hip_bf16.h>
#include <math.h>

// Sizes (fixed by the problem)
// V=50000, E=128, H=128, B=32, S=50, T=40, D=256, G=512 (4H), BS=B*S=1600

__device__ __forceinline__ float sigm(float x) { return 1.f / (1.f + expf(-x)); }

// ---------------------------------------------------------------------------
// Generic 2D transpose: in[z][R][C] -> out[z][C][R]
// ---------------------------------------------------------------------------
__global__ void transpose_k(const float* __restrict__ in, float* __restrict__ out,
                            int R, int C) {
    __shared__ float tile[32][33];
    int z = blockIdx.z;
    in += (size_t)z * R * C;
    out += (size_t)z * R * C;
    int bx = blockIdx.x * 32, by = blockIdx.y * 32;
    int tx = threadIdx.x, ty = threadIdx.y; // 32 x 8
    #pragma unroll
    for (int j = 0; j < 32; j += 8) {
        tile[ty + j][tx] = in[(size_t)(by + ty + j) * C + bx + tx];
    }
    __syncthreads();
    #pragma unroll
    for (int j = 0; j < 32; j += 8) {
        out[(size_t)(bx + ty + j) * R + by + tx] = tile[tx][ty + j];
    }
}

// ---------------------------------------------------------------------------
// Word-level BiLSTM scan. One WG = one direction x 16 sequences.
// 256 threads: k = tid&127 (hidden unit), hf = tid>>7 (seq-half: 8 seqs each).
// Thread owns gates {k, k+128, k+256, k+384} -> c/h update is thread-local.
// MODE 0: x = emb[ids] (fused gather), writes h to outp[(n*T+t)*256 + dir*128 + k]
// MODE 1: x = xin rows (256 floats), accumulates mean over t into sent.
// ---------------------------------------------------------------------------
template <int E, int MODE>
__global__ __launch_bounds__(256) void word_scan(
    const int* __restrict__ ids, const float* __restrict__ emb,
    const float* __restrict__ xin,
    const float* __restrict__ wihT,   // [2][E][512]
    const float* __restrict__ whhT,   // [2][128][512]
    const float* __restrict__ bias,   // [2][512]
    float* __restrict__ outp, int nGroups) {
    const int T = 40;
    static_assert(E % 16 == 0, "E");
    int wg = blockIdx.x;
    int dir = wg / nGroups;
    int grp = wg - dir * nGroups;
    int base = grp * 16;
    int tid = threadIdx.x;
    int k = tid & 127;
    int hf = tid >> 7;
    int h8 = hf * 8;

    __shared__ float xs[E][16];
    __shared__ float hs[128][16];

    const float* wih = wihT + (size_t)dir * E * 512;
    const float* whh = whhT + (size_t)dir * 128 * 512;
    const float* bb = bias + dir * 512;
    float bi = bb[k], bff = bb[128 + k], bg = bb[256 + k], bo = bb[384 + k];

    float c[8], ms[8];
    #pragma unroll
    for (int s = 0; s < 8; s++) { c[s] = 0.f; ms[s] = 0.f; }

    for (int t = 0; t < T; t++) {
        int te = dir ? (T - 1 - t) : t;
        // ---- stage x rows for the 16 seqs into xs[e][sl] ----
        {
            int sl = tid >> 4;
            const int CH = E / 16;
            int e0 = (tid & 15) * CH;
            int seq = base + sl;
            const float* row;
            if (MODE == 0) {
                int id = ids[(size_t)seq * T + te];
                row = emb + (size_t)id * 128;
            } else {
                row = xin + ((size_t)seq * T + te) * 256;
            }
            #pragma unroll
            for (int j = 0; j < CH; j += 4) {
                float4 v = *(const float4*)&row[e0 + j];
                xs[e0 + j + 0][sl] = v.x;
                xs[e0 + j + 1][sl] = v.y;
                xs[e0 + j + 2][sl] = v.z;
                xs[e0 + j + 3][sl] = v.w;
            }
        }
        __syncthreads();

        float a0[8], a1[8], a2[8], a3[8];
        #pragma unroll
        for (int s = 0; s < 8; s++) { a0[s] = a1[s] = a2[s] = a3[s] = 0.f; }

        // ---- x part: g += W_ih @ x ----
        for (int e = 0; e < E; e++) {
            const float* wr = wih + (size_t)e * 512;
            float w0 = wr[k], w1 = wr[128 + k], w2 = wr[256 + k], w3 = wr[384 + k];
            float4 x0 = *(const float4*)&xs[e][h8];
            float4 x1 = *(const float4*)&xs[e][h8 + 4];
            float v[8] = {x0.x, x0.y, x0.z, x0.w, x1.x, x1.y, x1.z, x1.w};
            #pragma unroll
            for (int s = 0; s < 8; s++) {
                a0[s] = fmaf(w0, v[s], a0[s]);
                a1[s] = fmaf(w1, v[s], a1[s]);
                a2[s] = fmaf(w2, v[s], a2[s]);
                a3[s] = fmaf(w3, v[s], a3[s]);
            }
        }
        // ---- h part: g += W_hh @ h_prev (h=0 at t==0) ----
        if (t > 0) {
            for (int r = 0; r < 128; r++) {
                const float* wr = whh + (size_t)r * 512;
                float w0 = wr[k], w1 = wr[128 + k], w2 = wr[256 + k], w3 = wr[384 + k];
                float4 x0 = *(const float4*)&hs[r][h8];
                float4 x1 = *(const float4*)&hs[r][h8 + 4];
                float v[8] = {x0.x, x0.y, x0.z, x0.w, x1.x, x1.y, x1.z, x1.w};
                #pragma unroll
                for (int s = 0; s < 8; s++) {
                    a0[s] = fmaf(w0, v[s], a0[s]);
                    a1[s] = fmaf(w1, v[s], a1[s]);
                    a2[s] = fmaf(w2, v[s], a2[s]);
                    a3[s] = fmaf(w3, v[s], a3[s]);
                }
            }
        }
        __syncthreads(); // everyone done reading hs/xs

        // ---- gates + state update (thread-local) ----
        #pragma unroll
        for (int s = 0; s < 8; s++) {
            float iv = sigm(a0[s] + bi);
            float fv = sigm(a1[s] + bff);
            float gv = tanhf(a2[s] + bg);
            float ov = sigm(a3[s] + bo);
            c[s] = fv * c[s] + iv * gv;
            float hv = ov * tanhf(c[s]);
            hs[k][h8 + s] = hv;
            if (MODE == 0) {
                outp[(((size_t)(base + h8 + s)) * T + te) * 256 + (size_t)dir * 128 + k] = hv;
            } else {
                ms[s] += hv;
            }
        }
        __syncthreads(); // hs ready for next step
    }
    if (MODE == 1) {
        #pragma unroll
        for (int s = 0; s < 8; s++) {
            outp[(size_t)(base + h8 + s) * 256 + (size_t)dir * 128 + k] = ms[s] * (1.f / T);
        }
    }
}

// ---------------------------------------------------------------------------
// Doc-level BiLSTM scan (32 sequences of length 50, input 256, hidden 128).
// One WG per (b, dir). 512 threads: k = tid&127, p = tid>>7 splits the
// 384-length dot product 4 ways; partials reduced through LDS.
// ---------------------------------------------------------------------------
__global__ __launch_bounds__(512) void doc_scan(
    const float* __restrict__ xin,   // [32*50][256]
    const float* __restrict__ wihT,  // [2][256][512]
    const float* __restrict__ whhT,  // [2][128][512]
    const float* __restrict__ bias,  // [2][512]
    float* __restrict__ outp) {      // [32*50][256]
    const int S = 50;
    int b = blockIdx.x >> 1, dir = blockIdx.x & 1;
    int tid = threadIdx.x;
    int k = tid & 127, p = tid >> 7;
    __shared__ float xs[256];
    __shared__ float hl[128];
    __shared__ float part[3][4][128];
    const float* wih = wihT + (size_t)dir * 256 * 512;
    const float* whh = whhT + (size_t)dir * 128 * 512;
    const float* bb = bias + dir * 512;
    float bi = bb[k], bff = bb[128 + k], bg = bb[256 + k], bo = bb[384 + k];
    float c = 0.f;
    for (int t = 0; t < S; t++) {
        int te = dir ? (S - 1 - t) : t;
        const float* row = xin + ((size_t)b * S + te) * 256;
        if (tid < 256) xs[tid] = row[tid];
        __syncthreads();
        float a0 = 0, a1 = 0, a2 = 0, a3 = 0;
        int lo = p * 96, hi = lo + 96;
        for (int r = lo; r < hi; r++) {
            float xv; const float* wr;
            if (r < 256) { xv = xs[r]; wr = wih + (size_t)r * 512; }
            else { if (t == 0) break; xv = hl[r - 256]; wr = whh + (size_t)(r - 256) * 512; }
            a0 = fmaf(wr[k], xv, a0);
            a1 = fmaf(wr[128 + k], xv, a1);
            a2 = fmaf(wr[256 + k], xv, a2);
            a3 = fmaf(wr[384 + k], xv, a3);
        }
        if (p > 0) {
            part[p - 1][0][k] = a0; part[p - 1][1][k] = a1;
            part[p - 1][2][k] = a2; part[p - 1][3][k] = a3;
        }
        __syncthreads();
        if (p == 0) {
            #pragma unroll
            for (int q = 0; q < 3; q++) {
                a0 += part[q][0][k]; a1 += part[q][1][k];
                a2 += part[q][2][k]; a3 += part[q][3][k];
            }
            float iv = sigm(a0 + bi);
            float fv = sigm(a1 + bff);
            float gv = tanhf(a2 + bg);
            float ov = sigm(a3 + bo);
            c = fv * c + iv * gv;
            float hv = ov * tanhf(c);
            hl[k] = hv;
            outp[((size_t)b * S + te) * 256 + (size_t)dir * 128 + k] = hv;
        }
        __syncthreads();
    }
}

// ---------------------------------------------------------------------------
// Head: doc_emb, content+salience (pred), then the 50-step novelty scan.
// One WG per batch item b. out[b] (50x256) staged in LDS (stride 257).
// ---------------------------------------------------------------------------
__global__ __launch_bounds__(256) void head_kernel(
    const float* __restrict__ outv,      // [32][50][256]
    const float* __restrict__ content_w, // [256]
    const float* __restrict__ content_b, // [1]
    const float* __restrict__ doclT,     // [256][256] (transposed)
    const float* __restrict__ docl_b,    // [256]
    const float* __restrict__ salT,      // [256][256]
    const float* __restrict__ sal_b,     // [256]
    const float* __restrict__ novT,      // [256][256]
    const float* __restrict__ nov_b,     // [256]
    float* __restrict__ outp) {          // [32][50]
    const int S = 50, D = 256;
    int b = blockIdx.x;
    int tid = threadIdx.x;
    __shared__ float oL[50][257];
    __shared__ float mb[256];
    __shared__ float de[256];
    __shared__ float svec[256];
    __shared__ float nvec[256];
    __shared__ float tsum[256];
    __shared__ float predL[64];
    __shared__ float nvL[64];
    __shared__ float red[4][64];

    const float* ob = outv + (size_t)b * S * D;
    for (int i = tid; i < S * D; i += 256) {
        int s = i >> 8, d = i & 255;
        oL[s][d] = ob[i];
    }
    __syncthreads();
    // mean over s
    {
        float m = 0;
        for (int s = 0; s < S; s++) m += oL[s][tid];
        mb[tid] = m * (1.f / S);
    }
    __syncthreads();
    // doc_emb = tanh(mean @ docl_w.T + docl_b)
    {
        float acc = docl_b[tid];
        for (int d = 0; d < D; d++) acc = fmaf(doclT[d * 256 + tid], mb[d], acc);
        de[tid] = tanhf(acc);
    }
    __syncthreads();
    // sal_vec = doc_emb @ sal_w.T + sal_b
    {
        float acc = sal_b[tid];
        for (int d = 0; d < D; d++) acc = fmaf(salT[d * 256 + tid], de[d], acc);
        svec[tid] = acc;
    }
    __syncthreads();
    // pred[s] = content[s] + salience[s]
    {
        int s = tid & 63, pw = tid >> 6;
        float ca = 0, sa = 0;
        if (s < S) {
            for (int i = 0; i < 64; i++) {
                int d = pw * 64 + i;
                float ov = oL[s][d];
                ca = fmaf(ov, content_w[d], ca);
                sa = fmaf(ov, svec[d], sa);
            }
        }
        red[pw][s] = ca + sa;
    }
    __syncthreads();
    if (tid < S) {
        predL[tid] = content_b[0] + red[0][tid] + red[1][tid] + red[2][tid] + red[3][tid];
    }
    float summ = 0.f; // summary[tid] lives in a register
    __syncthreads();
    for (int it = 0; it < S; ++it) {
        tsum[tid] = tanhf(summ);
        __syncthreads();
        // nov_vec = tanh(summary) @ nov_w.T + nov_b
        {
            float acc = nov_b[tid];
            for (int d = 0; d < D; d++) acc = fmaf(novT[d * 256 + tid], tsum[d], acc);
            nvec[tid] = acc;
        }
        __syncthreads();
        // nov[s] = out[s] . nov_vec
        {
            int s = tid & 63, pw = tid >> 6;
            float na = 0;
            if (s < S) {
                for (int i = 0; i < 64; i++) {
                    int d = pw * 64 + i;
                    na = fmaf(oL[s][d], nvec[d], na);
                }
            }
            red[pw][s] = na;
        }
        __syncthreads();
        if (tid < S) nvL[tid] = red[0][tid] + red[1][tid] + red[2][tid] + red[3][tid];
        __syncthreads();
        float prob = sigm(predL[it] - nvL[it]);
        summ = fmaf(prob, oL[it][tid], summ);
        // no barrier needed: next writes to tsum are own-thread; nvL/red rewrites
        // are separated from these reads by the barriers above.
        __syncthreads();
    }
    if (tid < S) outp[(size_t)b * S + tid] = predL[tid] - nvL[tid];
}

// ---------------------------------------------------------------------------
extern "C" void kernel_launch(void* const* d_in, const int* in_sizes, int n_in,
                              void* d_out, int out_size, void* d_ws, size_t ws_size,
                              hipStream_t stream) {
    const int* ids = (const int*)d_in[0];
    const float* emb = (const float*)d_in[1];
    const float* e_ih0 = (const float*)d_in[2];
    const float* e_hh0 = (const float*)d_in[3];
    const float* e_b0 = (const float*)d_in[4];
    const float* e_ih1 = (const float*)d_in[5];
    const float* e_hh1 = (const float*)d_in[6];
    const float* e_b1 = (const float*)d_in[7];
    const float* d_ih0 = (const float*)d_in[8];
    const float* d_hh0 = (const float*)d_in[9];
    const float* d_b0 = (const float*)d_in[10];
    const float* d_ih1 = (const float*)d_in[11];
    const float* d_hh1 = (const float*)d_in[12];
    const float* d_b1 = (const float*)d_in[13];
    const float* content_w = (const float*)d_in[14];
    const float* content_b = (const float*)d_in[15];
    const float* docl_w = (const float*)d_in[16];
    const float* docl_b = (const float*)d_in[17];
    const float* sal_w = (const float*)d_in[18];
    const float* sal_b = (const float*)d_in[19];
    const float* nov_w = (const float*)d_in[20];
    const float* nov_b = (const float*)d_in[21];
    float* outp = (float*)d_out;

    float* ws = (float*)d_ws;
    size_t off = 0;
    auto alloc = [&](size_t n) { float* p = ws + off; off += n; return p; };
    float* wT_eih0 = alloc((size_t)2 * 128 * 512);
    float* wT_ehh0 = alloc((size_t)2 * 128 * 512);
    float* wT_eih1 = alloc((size_t)2 * 256 * 512);
    float* wT_ehh1 = alloc((size_t)2 * 128 * 512);
    float* wT_dih0 = alloc((size_t)2 * 256 * 512);
    float* wT_dhh0 = alloc((size_t)2 * 128 * 512);
    float* wT_dih1 = alloc((size_t)2 * 256 * 512);
    float* wT_dhh1 = alloc((size_t)2 * 128 * 512);
    float* wT_docl = alloc((size_t)256 * 256);
    float* wT_sal = alloc((size_t)256 * 256);
    float* wT_nov = alloc((size_t)256 * 256);
    float* h0out = alloc((size_t)1600 * 40 * 256);
    float* sent = alloc((size_t)1600 * 256);
    float* d0out = alloc((size_t)1600 * 256);
    float* dout = alloc((size_t)1600 * 256);
    (void)ws_size; (void)in_sizes; (void)n_in; (void)out_size;

    dim3 tb(32, 8);
    // weight transposes: [z][R][C] -> [z][C][R]
    transpose_k<<<dim3(128 / 32, 512 / 32, 2), tb, 0, stream>>>(e_ih0, wT_eih0, 512, 128);
    transpose_k<<<dim3(128 / 32, 512 / 32, 2), tb, 0, stream>>>(e_hh0, wT_ehh0, 512, 128);
    transpose_k<<<dim3(256 / 32, 512 / 32, 2), tb, 0, stream>>>(e_ih1, wT_eih1, 512, 256);
    transpose_k<<<dim3(128 / 32, 512 / 32, 2), tb, 0, stream>>>(e_hh1, wT_ehh1, 512, 128);
    transpose_k<<<dim3(256 / 32, 512 / 32, 2), tb, 0, stream>>>(d_ih0, wT_dih0, 512, 256);
    transpose_k<<<dim3(128 / 32, 512 / 32, 2), tb, 0, stream>>>(d_hh0, wT_dhh0, 512, 128);
    transpose_k<<<dim3(256 / 32, 512 / 32, 2), tb, 0, stream>>>(d_ih1, wT_dih1, 512, 256);
    transpose_k<<<dim3(128 / 32, 512 / 32, 2), tb, 0, stream>>>(d_hh1, wT_dhh1, 512, 128);
    transpose_k<<<dim3(256 / 32, 256 / 32, 1), tb, 0, stream>>>(docl_w, wT_docl, 256, 256);
    transpose_k<<<dim3(256 / 32, 256 / 32, 1), tb, 0, stream>>>(sal_w, wT_sal, 256, 256);
    transpose_k<<<dim3(256 / 32, 256 / 32, 1), tb, 0, stream>>>(nov_w, wT_nov, 256, 256);

    // word-level BiLSTM layers (1600 seqs, T=40); 100 groups x 2 dirs
    word_scan<128, 0><<<200, 256, 0, stream>>>(ids, emb, nullptr, wT_eih0, wT_ehh0,
                                               e_b0, h0out, 100);
    word_scan<256, 1><<<200, 256, 0, stream>>>(nullptr, nullptr, h0out, wT_eih1, wT_ehh1,
                                               e_b1, sent, 100);
    // doc-level BiLSTM layers (32 seqs, S=50)
    doc_scan<<<64, 512, 0, stream>>>(sent, wT_dih0, wT_dhh0, d_b0, d0out);
    doc_scan<<<64, 512, 0, stream>>>(d0out, wT_dih1, wT_dhh1, d_b1, dout);
    // head
    head_kernel<<<32, 256, 0, stream>>>(dout, content_w, content_b, wT_docl, docl_b,
                                        wT_sal, sal_b, wT_nov, nov_b, outp);
}

// Round 4
// 2508.043 us; speedup vs baseline: 1.9084x; 1.9084x over previous
//
#include <hip/hip_runtime.h>
#include <hip/hip_bf16.h>
#include <math.h>

// Sizes: V=50000, E=128, H=128, B=32, S=50, T=40, D=256, G=512 (4H), BS=1600

__device__ __forceinline__ float sigm(float x) { return 1.f / (1.f + expf(-x)); }

// ---------------------------------------------------------------------------
// Generic 2D transpose: in[z][R][C] -> out[z][C][R]
// ---------------------------------------------------------------------------
__global__ void transpose_k(const float* __restrict__ in, float* __restrict__ out,
                            int R, int C) {
    __shared__ float tile[32][33];
    int z = blockIdx.z;
    in += (size_t)z * R * C;
    out += (size_t)z * R * C;
    int bx = blockIdx.x * 32, by = blockIdx.y * 32;
    int tx = threadIdx.x, ty = threadIdx.y; // 32 x 8
    #pragma unroll
    for (int j = 0; j < 32; j += 8) {
        tile[ty + j][tx] = in[(size_t)(by + ty + j) * C + bx + tx];
    }
    __syncthreads();
    #pragma unroll
    for (int j = 0; j < 32; j += 8) {
        out[(size_t)(bx + ty + j) * R + by + tx] = tile[tx][ty + j];
    }
}

// ---------------------------------------------------------------------------
// Pack word-layer weights: dst[dir][r][k][g] (r: ih rows 0..E-1 then hh rows)
// from ih[dir][512][E], hh[dir][512][128]; gate row g*128+k.
// ---------------------------------------------------------------------------
__global__ void pack_w(const float* __restrict__ ih, const float* __restrict__ hh,
                       float* __restrict__ dst, int E) {
    int ROWS = E + 128;
    size_t total = (size_t)2 * ROWS * 512;
    for (size_t i = (size_t)blockIdx.x * 256 + threadIdx.x; i < total;
         i += (size_t)gridDim.x * 256) {
        int g = (int)(i & 3);
        int k = (int)((i >> 2) & 127);
        size_t rr = i >> 9;
        int r = (int)(rr % ROWS);
        int dir = (int)(rr / ROWS);
        float v = (r < E) ? ih[((size_t)dir * 512 + g * 128 + k) * E + r]
                          : hh[((size_t)dir * 512 + g * 128 + k) * 128 + (r - E)];
        dst[i] = v;
    }
}

// ---------------------------------------------------------------------------
// Word-level BiLSTM scan v2. One WG = (dir, 16-seq group); 200 WGs x 512 thr.
// tid -> k = tid&127 (hidden unit), gp = (tid>>7)&1 (gate pair: 0=(i,f),
// 1=(g,o)), hf = tid>>8 (seq half: 8 seqs each). Weights packed [row][k][4],
// loaded as float2 per row (coalesced 512B/wave). x/h staged in LDS, read as
// aligned b128 broadcasts. Gate exchange (g,o) via LDS; state on gp==0.
// MODE 0: x = emb[ids], writes h to outp[(seq*T+t)*256 + dir*128 + k]
// MODE 1: x = xin rows (256), accumulates mean over t into outp[seq][...].
// ---------------------------------------------------------------------------
template <int E, int MODE>
__global__ __launch_bounds__(512) void word_scan2(
    const int* __restrict__ ids, const float* __restrict__ emb,
    const float* __restrict__ xin,
    const float* __restrict__ wpk,   // [2][E+128][128][4]
    const float* __restrict__ bias,  // [2][512]
    float* __restrict__ outp) {
    const int T = 40;
    const int ROWS = E + 128;
    int wg = blockIdx.x;
    int dir = wg / 100;
    int grp = wg - dir * 100;
    int base = grp * 16;
    int tid = threadIdx.x;
    int k = tid & 127;
    int gp = (tid >> 7) & 1;
    int hf = tid >> 8;
    int sb = hf * 8;

    __shared__ float xs[E][20];
    __shared__ float hs[128][20];
    __shared__ float pa[2][128][17];

    const float* wp = wpk + (size_t)dir * ROWS * 512 + k * 4 + gp * 2;
    const float* bb = bias + dir * 512;
    float bi = bb[k], bf_ = bb[128 + k], bg = bb[256 + k], bo = bb[384 + k];

    float c[8], ms[8];
    #pragma unroll
    for (int j = 0; j < 8; j++) { c[j] = 0.f; ms[j] = 0.f; }

    for (int t = 0; t < T; t++) {
        int te = dir ? (T - 1 - t) : t;
        // ---- stage x rows for the 16 seqs into xs[e][s] ----
        {
            const int NF4 = 16 * (E / 4);
            for (int idx = tid; idx < NF4; idx += 512) {
                int s = idx / (E / 4);
                int e4 = idx - s * (E / 4);
                int seq = base + s;
                float4 v;
                if (MODE == 0) {
                    int id = ids[(size_t)seq * T + te];
                    v = *(const float4*)&emb[(size_t)id * 128 + e4 * 4];
                } else {
                    v = *(const float4*)&xin[((size_t)seq * T + te) * 256 + e4 * 4];
                }
                xs[e4 * 4 + 0][s] = v.x;
                xs[e4 * 4 + 1][s] = v.y;
                xs[e4 * 4 + 2][s] = v.z;
                xs[e4 * 4 + 3][s] = v.w;
            }
        }
        __syncthreads();

        float a0[8], a1[8];
        #pragma unroll
        for (int j = 0; j < 8; j++) { a0[j] = 0.f; a1[j] = 0.f; }

        // ---- x part ----
        #pragma unroll 4
        for (int e = 0; e < E; e++) {
            const float2 w = *(const float2*)(wp + (size_t)e * 512);
            const float4 x0 = *(const float4*)&xs[e][sb];
            const float4 x1 = *(const float4*)&xs[e][sb + 4];
            const float xv[8] = {x0.x, x0.y, x0.z, x0.w, x1.x, x1.y, x1.z, x1.w};
            #pragma unroll
            for (int j = 0; j < 8; j++) {
                a0[j] = fmaf(w.x, xv[j], a0[j]);
                a1[j] = fmaf(w.y, xv[j], a1[j]);
            }
        }
        // ---- h part ----
        if (t > 0) {
            const float* wh = wp + (size_t)E * 512;
            #pragma unroll 4
            for (int r = 0; r < 128; r++) {
                const float2 w = *(const float2*)(wh + (size_t)r * 512);
                const float4 x0 = *(const float4*)&hs[r][sb];
                const float4 x1 = *(const float4*)&hs[r][sb + 4];
                const float xv[8] = {x0.x, x0.y, x0.z, x0.w, x1.x, x1.y, x1.z, x1.w};
                #pragma unroll
                for (int j = 0; j < 8; j++) {
                    a0[j] = fmaf(w.x, xv[j], a0[j]);
                    a1[j] = fmaf(w.y, xv[j], a1[j]);
                }
            }
        }

        // ---- exchange (g,o) pre-activations; gp0 updates state ----
        if (gp == 1) {
            #pragma unroll
            for (int j = 0; j < 8; j++) {
                pa[0][k][sb + j] = a0[j];  // g-gate preact
                pa[1][k][sb + j] = a1[j];  // o-gate preact
            }
        }
        __syncthreads();
        if (gp == 0) {
            float hv[8];
            #pragma unroll
            for (int j = 0; j < 8; j++) {
                float iv = sigm(a0[j] + bi);
                float fv = sigm(a1[j] + bf_);
                float gv = tanhf(pa[0][k][sb + j] + bg);
                float ov = sigm(pa[1][k][sb + j] + bo);
                c[j] = fv * c[j] + iv * gv;
                hv[j] = ov * tanhf(c[j]);
            }
            *(float4*)&hs[k][sb] = make_float4(hv[0], hv[1], hv[2], hv[3]);
            *(float4*)&hs[k][sb + 4] = make_float4(hv[4], hv[5], hv[6], hv[7]);
            if (MODE == 0) {
                #pragma unroll
                for (int j = 0; j < 8; j++) {
                    outp[(((size_t)(base + sb + j)) * T + te) * 256 +
                         (size_t)dir * 128 + k] = hv[j];
                }
            } else {
                #pragma unroll
                for (int j = 0; j < 8; j++) ms[j] += hv[j];
            }
        }
        __syncthreads();
    }
    if (MODE == 1 && gp == 0) {
        #pragma unroll
        for (int j = 0; j < 8; j++) {
            outp[(size_t)(base + sb + j) * 256 + (size_t)dir * 128 + k] =
                ms[j] * (1.f / T);
        }
    }
}

// ---------------------------------------------------------------------------
// Small fp32 GEMM: C[dir][n][g] = A[n][:256] @ Bt[dir][256][512] + bias[dir][g]
// 64x64 tiles, K=256, 256 threads, 4x4 micro-tile.
// ---------------------------------------------------------------------------
__global__ __launch_bounds__(256) void gemm_pre(
    const float* __restrict__ A, const float* __restrict__ Bt,
    const float* __restrict__ bias, float* __restrict__ C) {
    int dir = blockIdx.z;
    const float* B = Bt + (size_t)dir * 256 * 512;
    float* Cp = C + (size_t)dir * 1600 * 512;
    const float* bb = bias + (size_t)dir * 512;
    int n0 = blockIdx.x * 64, g0 = blockIdx.y * 64;
    int tid = threadIdx.x;
    int tx = tid & 15, ty = tid >> 4;
    __shared__ float AsT[32][72];
    __shared__ float Bs[32][72];
    float acc[4][4];
    #pragma unroll
    for (int i = 0; i < 4; i++)
        #pragma unroll
        for (int j = 0; j < 4; j++) acc[i][j] = 0.f;

    for (int k0 = 0; k0 < 256; k0 += 32) {
        #pragma unroll
        for (int it = 0; it < 2; it++) {
            int idx = tid + it * 256;
            int n = idx & 63, e4 = idx >> 6;
            float4 v = *(const float4*)&A[(size_t)(n0 + n) * 256 + k0 + e4 * 4];
            AsT[e4 * 4 + 0][n] = v.x;
            AsT[e4 * 4 + 1][n] = v.y;
            AsT[e4 * 4 + 2][n] = v.z;
            AsT[e4 * 4 + 3][n] = v.w;
        }
        #pragma unroll
        for (int it = 0; it < 2; it++) {
            int idx = tid + it * 256;
            int g4 = idx & 15, e = idx >> 4;
            float4 v = *(const float4*)&B[(size_t)(k0 + e) * 512 + g0 + g4 * 4];
            *(float4*)&Bs[e][g4 * 4] = v;
        }
        __syncthreads();
        #pragma unroll 8
        for (int kk = 0; kk < 32; kk++) {
            float4 a = *(const float4*)&AsT[kk][ty * 4];
            float4 b = *(const float4*)&Bs[kk][tx * 4];
            const float av[4] = {a.x, a.y, a.z, a.w};
            const float bv[4] = {b.x, b.y, b.z, b.w};
            #pragma unroll
            for (int i = 0; i < 4; i++)
                #pragma unroll
                for (int j = 0; j < 4; j++)
                    acc[i][j] = fmaf(av[i], bv[j], acc[i][j]);
        }
        __syncthreads();
    }
    #pragma unroll
    for (int i = 0; i < 4; i++) {
        #pragma unroll
        for (int j = 0; j < 4; j++) {
            Cp[(size_t)(n0 + ty * 4 + i) * 512 + g0 + tx * 4 + j] =
                acc[i][j] + bb[g0 + tx * 4 + j];
        }
    }
}

// ---------------------------------------------------------------------------
// Doc-level BiLSTM scan v2: recurrent part only (input GEMM precomputed with
// bias folded). One WG = (dir, 2 batch items); 32 WGs x 512 thr (g = gate col).
// ---------------------------------------------------------------------------
__global__ __launch_bounds__(512) void doc_scan2(
    const float* __restrict__ pre,  // [2][32][50][512] (bias included)
    const float* __restrict__ whh,  // [2][128][512]
    float* __restrict__ outp) {     // [1600][256]
    const int S = 50;
    int wg = blockIdx.x;  // 32
    int dir = wg >> 4;
    int b0 = (wg & 15) * 2;
    int g = threadIdx.x;
    int k = g & 127, su = g >> 7;  // update mapping (g < 256)
    __shared__ float hsd[2][128];
    __shared__ float paD[2][512];
    const float* W = whh + (size_t)dir * 128 * 512;
    const float* p0 = pre + ((size_t)dir * 1600 + (size_t)b0 * 50) * 512;
    float cst = 0.f;
    for (int t = 0; t < S; t++) {
        int te = dir ? (S - 1 - t) : t;
        float a0 = p0[(size_t)te * 512 + g];
        float a1 = p0[((size_t)(50 + te)) * 512 + g];
        if (t > 0) {
            #pragma unroll 8
            for (int r = 0; r < 128; r++) {
                float w = W[(size_t)r * 512 + g];
                a0 = fmaf(w, hsd[0][r], a0);
                a1 = fmaf(w, hsd[1][r], a1);
            }
        }
        paD[0][g] = a0;
        paD[1][g] = a1;
        __syncthreads();
        if (g < 256) {
            float pi = paD[su][k], pf = paD[su][128 + k];
            float pg = paD[su][256 + k], po = paD[su][384 + k];
            float iv = sigm(pi), fv = sigm(pf), gv = tanhf(pg), ov = sigm(po);
            cst = fv * cst + iv * gv;
            float hv = ov * tanhf(cst);
            hsd[su][k] = hv;
            outp[((size_t)(b0 + su) * 50 + te) * 256 + (size_t)dir * 128 + k] = hv;
        }
        __syncthreads();
    }
}

// ---------------------------------------------------------------------------
// Head: doc_emb, content+salience (pred), then the 50-step novelty scan.
// One WG per batch item b. out[b] (50x256) staged in LDS (stride 257).
// ---------------------------------------------------------------------------
__global__ __launch_bounds__(256) void head_kernel(
    const float* __restrict__ outv,      // [32][50][256]
    const float* __restrict__ content_w, // [256]
    const float* __restrict__ content_b, // [1]
    const float* __restrict__ doclT,     // [256][256] (transposed)
    const float* __restrict__ docl_b,    // [256]
    const float* __restrict__ salT,      // [256][256]
    const float* __restrict__ sal_b,     // [256]
    const float* __restrict__ novT,      // [256][256]
    const float* __restrict__ nov_b,     // [256]
    float* __restrict__ outp) {          // [32][50]
    const int S = 50, D = 256;
    int b = blockIdx.x;
    int tid = threadIdx.x;
    __shared__ float oL[50][257];
    __shared__ float mb[256];
    __shared__ float de[256];
    __shared__ float svec[256];
    __shared__ float nvec[256];
    __shared__ float tsum[256];
    __shared__ float predL[64];
    __shared__ float nvL[64];
    __shared__ float red[4][64];

    const float* ob = outv + (size_t)b * S * D;
    for (int i = tid; i < S * D; i += 256) {
        int s = i >> 8, d = i & 255;
        oL[s][d] = ob[i];
    }
    __syncthreads();
    {
        float m = 0;
        for (int s = 0; s < S; s++) m += oL[s][tid];
        mb[tid] = m * (1.f / S);
    }
    __syncthreads();
    {
        float acc = docl_b[tid];
        for (int d = 0; d < D; d++) acc = fmaf(doclT[d * 256 + tid], mb[d], acc);
        de[tid] = tanhf(acc);
    }
    __syncthreads();
    {
        float acc = sal_b[tid];
        for (int d = 0; d < D; d++) acc = fmaf(salT[d * 256 + tid], de[d], acc);
        svec[tid] = acc;
    }
    __syncthreads();
    {
        int s = tid & 63, pw = tid >> 6;
        float ca = 0, sa = 0;
        if (s < S) {
            for (int i = 0; i < 64; i++) {
                int d = pw * 64 + i;
                float ov = oL[s][d];
                ca = fmaf(ov, content_w[d], ca);
                sa = fmaf(ov, svec[d], sa);
            }
        }
        red[pw][s] = ca + sa;
    }
    __syncthreads();
    if (tid < S) {
        predL[tid] = content_b[0] + red[0][tid] + red[1][tid] + red[2][tid] + red[3][tid];
    }
    float summ = 0.f;
    __syncthreads();
    for (int it = 0; it < S; ++it) {
        tsum[tid] = tanhf(summ);
        __syncthreads();
        {
            float acc = nov_b[tid];
            for (int d = 0; d < D; d++) acc = fmaf(novT[d * 256 + tid], tsum[d], acc);
            nvec[tid] = acc;
        }
        __syncthreads();
        {
            int s = tid & 63, pw = tid >> 6;
            float na = 0;
            if (s < S) {
                for (int i = 0; i < 64; i++) {
                    int d = pw * 64 + i;
                    na = fmaf(oL[s][d], nvec[d], na);
                }
            }
            red[pw][s] = na;
        }
        __syncthreads();
        if (tid < S) nvL[tid] = red[0][tid] + red[1][tid] + red[2][tid] + red[3][tid];
        __syncthreads();
        float prob = sigm(predL[it] - nvL[it]);
        summ = fmaf(prob, oL[it][tid], summ);
        __syncthreads();
    }
    if (tid < S) outp[(size_t)b * S + tid] = predL[tid] - nvL[tid];
}

// ---------------------------------------------------------------------------
extern "C" void kernel_launch(void* const* d_in, const int* in_sizes, int n_in,
                              void* d_out, int out_size, void* d_ws, size_t ws_size,
                              hipStream_t stream) {
    const int* ids = (const int*)d_in[0];
    const float* emb = (const float*)d_in[1];
    const float* e_ih0 = (const float*)d_in[2];
    const float* e_hh0 = (const float*)d_in[3];
    const float* e_b0 = (const float*)d_in[4];
    const float* e_ih1 = (const float*)d_in[5];
    const float* e_hh1 = (const float*)d_in[6];
    const float* e_b1 = (const float*)d_in[7];
    const float* d_ih0 = (const float*)d_in[8];
    const float* d_hh0 = (const float*)d_in[9];
    const float* d_b0 = (const float*)d_in[10];
    const float* d_ih1 = (const float*)d_in[11];
    const float* d_hh1 = (const float*)d_in[12];
    const float* d_b1 = (const float*)d_in[13];
    const float* content_w = (const float*)d_in[14];
    const float* content_b = (const float*)d_in[15];
    const float* docl_w = (const float*)d_in[16];
    const float* docl_b = (const float*)d_in[17];
    const float* sal_w = (const float*)d_in[18];
    const float* sal_b = (const float*)d_in[19];
    const float* nov_w = (const float*)d_in[20];
    const float* nov_b = (const float*)d_in[21];
    float* outp = (float*)d_out;

    float* ws = (float*)d_ws;
    size_t off = 0;
    auto alloc = [&](size_t n) { float* p = ws + off; off += n; return p; };
    float* wpk0 = alloc((size_t)2 * 256 * 512);     // word L0 packed
    float* wpk1 = alloc((size_t)2 * 384 * 512);     // word L1 packed
    float* bT_d0 = alloc((size_t)2 * 256 * 512);
    float* whh_d0 = alloc((size_t)2 * 128 * 512);
    float* bT_d1 = alloc((size_t)2 * 256 * 512);
    float* whh_d1 = alloc((size_t)2 * 128 * 512);
    float* wT_docl = alloc((size_t)256 * 256);
    float* wT_sal = alloc((size_t)256 * 256);
    float* wT_nov = alloc((size_t)256 * 256);
    float* h0out = alloc((size_t)1600 * 40 * 256);
    float* sent = alloc((size_t)1600 * 256);
    float* pre_d0 = alloc((size_t)2 * 1600 * 512);
    float* d0out = alloc((size_t)1600 * 256);
    float* pre_d1 = alloc((size_t)2 * 1600 * 512);
    float* dout = alloc((size_t)1600 * 256);
    (void)ws_size; (void)in_sizes; (void)n_in; (void)out_size;

    dim3 tb(32, 8);
    // weight prep
    pack_w<<<1024, 256, 0, stream>>>(e_ih0, e_hh0, wpk0, 128);
    pack_w<<<1536, 256, 0, stream>>>(e_ih1, e_hh1, wpk1, 256);
    transpose_k<<<dim3(256 / 32, 512 / 32, 2), tb, 0, stream>>>(d_ih0, bT_d0, 512, 256);
    transpose_k<<<dim3(128 / 32, 512 / 32, 2), tb, 0, stream>>>(d_hh0, whh_d0, 512, 128);
    transpose_k<<<dim3(256 / 32, 512 / 32, 2), tb, 0, stream>>>(d_ih1, bT_d1, 512, 256);
    transpose_k<<<dim3(128 / 32, 512 / 32, 2), tb, 0, stream>>>(d_hh1, whh_d1, 512, 128);
    transpose_k<<<dim3(256 / 32, 256 / 32, 1), tb, 0, stream>>>(docl_w, wT_docl, 256, 256);
    transpose_k<<<dim3(256 / 32, 256 / 32, 1), tb, 0, stream>>>(sal_w, wT_sal, 256, 256);
    transpose_k<<<dim3(256 / 32, 256 / 32, 1), tb, 0, stream>>>(nov_w, wT_nov, 256, 256);

    // word-level BiLSTM layers (1600 seqs, T=40); 100 groups x 2 dirs
    word_scan2<128, 0><<<200, 512, 0, stream>>>(ids, emb, nullptr, wpk0, e_b0, h0out);
    word_scan2<256, 1><<<200, 512, 0, stream>>>(nullptr, nullptr, h0out, wpk1, e_b1, sent);

    // doc-level BiLSTM layers: input GEMM (bias folded) + recurrent scan
    gemm_pre<<<dim3(25, 8, 2), 256, 0, stream>>>(sent, bT_d0, d_b0, pre_d0);
    doc_scan2<<<32, 512, 0, stream>>>(pre_d0, whh_d0, d0out);
    gemm_pre<<<dim3(25, 8, 2), 256, 0, stream>>>(d0out, bT_d1, d_b1, pre_d1);
    doc_scan2<<<32, 512, 0, stream>>>(pre_d1, whh_d1, dout);

    // head
    head_kernel<<<32, 256, 0, stream>>>(dout, content_w, content_b, wT_docl, docl_b,
                                        wT_sal, sal_b, wT_nov, nov_b, outp);
}

// Round 8
// 2500.758 us; speedup vs baseline: 1.9140x; 1.0029x over previous
//
#include <hip/hip_runtime.h>
#include <hip/hip_bf16.h>
#include <math.h>

// Sizes: V=50000, E=128, H=128, B=32, S=50, T=40, D=256, G=512 (4H), BS=1600
// M = BS*T = 64000 seq-steps for word layers.

__device__ __forceinline__ float sigm(float x) { return 1.f / (1.f + expf(-x)); }

// ---------------------------------------------------------------------------
// Generic 2D transpose: in[z][R][C] -> out[z][C][R]
// ---------------------------------------------------------------------------
__global__ void transpose_k(const float* __restrict__ in, float* __restrict__ out,
                            int R, int C) {
    __shared__ float tile[32][33];
    int z = blockIdx.z;
    in += (size_t)z * R * C;
    out += (size_t)z * R * C;
    int bx = blockIdx.x * 32, by = blockIdx.y * 32;
    int tx = threadIdx.x, ty = threadIdx.y; // 32 x 8
    #pragma unroll
    for (int j = 0; j < 32; j += 8) {
        tile[ty + j][tx] = in[(size_t)(by + ty + j) * C + bx + tx];
    }
    __syncthreads();
    #pragma unroll
    for (int j = 0; j < 32; j += 8) {
        out[(size_t)(bx + ty + j) * R + by + tx] = tile[tx][ty + j];
    }
}

// ---------------------------------------------------------------------------
// Pack word-layer weights: dst[dir][r][k][g] (r: ih rows 0..E-1 then hh rows)
// from ih[dir][512][E], hh[dir][512][128]; gate row g*128+k.  (E=0 -> hh only)
// ---------------------------------------------------------------------------
__global__ void pack_w(const float* __restrict__ ih, const float* __restrict__ hh,
                       float* __restrict__ dst, int E) {
    int ROWS = E + 128;
    size_t total = (size_t)2 * ROWS * 512;
    for (size_t i = (size_t)blockIdx.x * 256 + threadIdx.x; i < total;
         i += (size_t)gridDim.x * 256) {
        int g = (int)(i & 3);
        int k = (int)((i >> 2) & 127);
        size_t rr = i >> 9;
        int r = (int)(rr % ROWS);
        int dir = (int)(rr / ROWS);
        float v = (r < E) ? ih[((size_t)dir * 512 + g * 128 + k) * E + r]
                          : hh[((size_t)dir * 512 + g * 128 + k) * 128 + (r - E)];
        dst[i] = v;
    }
}

// ---------------------------------------------------------------------------
// Pack W_ih for the x-part GEMM:  bt[e][c] with c = dir*512 + (gate*128+k),
// from ih[dir][512][E]. Also bias vector bv[c] from b[dir][512].
// ---------------------------------------------------------------------------
__global__ void pack_bt(const float* __restrict__ ih, const float* __restrict__ b,
                        float* __restrict__ bt, float* __restrict__ bv, int E) {
    size_t total = (size_t)E * 1024;
    for (size_t i = (size_t)blockIdx.x * 256 + threadIdx.x; i < total;
         i += (size_t)gridDim.x * 256) {
        int c = (int)(i & 1023);
        int e = (int)(i >> 10);
        int dir = c >> 9;
        int gk = c & 511;
        bt[i] = ih[((size_t)dir * 512 + gk) * E + e];
        if (e == 0) bv[c] = b[dir * 512 + gk];
    }
}

// ---------------------------------------------------------------------------
// x-part GEMM:  pre[n][c] = A[n][:K] @ bt[K][1024] + bv[c]
//   GATHER=1: A row n = emb[ids[n]] (K=128).  GATHER=0: A row n = A[n*K].
// 128x128 tiles, BK=32, 256 threads, 8x8 micro-tile. grid (M/128, 8).
// ---------------------------------------------------------------------------
template <int K, int GATHER>
__global__ __launch_bounds__(256, 4) void gemm_x(
    const float* __restrict__ A, const int* __restrict__ ids,
    const float* __restrict__ emb, const float* __restrict__ bt,
    const float* __restrict__ bv, float* __restrict__ C) {
    int n0 = blockIdx.x * 128;
    int c0 = blockIdx.y * 128;
    int tid = threadIdx.x;
    int tx = tid & 15, ty = tid >> 4;
    __shared__ float As[32][132]; // [kk][row]
    __shared__ float Bs[32][132]; // [kk][col]
    float acc[8][8];
    #pragma unroll
    for (int i = 0; i < 8; i++)
        #pragma unroll
        for (int j = 0; j < 8; j++) acc[i][j] = 0.f;

    for (int k0 = 0; k0 < K; k0 += 32) {
        // stage A (128 rows x 32 k): 1024 float4s, 4 per thread
        #pragma unroll
        for (int it = 0; it < 4; it++) {
            int lin = tid + it * 256;
            int r = lin >> 3, kq = lin & 7;
            const float* src;
            if (GATHER) {
                src = emb + (size_t)ids[n0 + r] * 128;
            } else {
                src = A + (size_t)(n0 + r) * K;
            }
            float4 v = *(const float4*)&src[k0 + kq * 4];
            As[kq * 4 + 0][r] = v.x;
            As[kq * 4 + 1][r] = v.y;
            As[kq * 4 + 2][r] = v.z;
            As[kq * 4 + 3][r] = v.w;
        }
        // stage B (32 k x 128 cols)
        #pragma unroll
        for (int it = 0; it < 4; it++) {
            int lin = tid + it * 256;
            int kk = lin >> 5, c4 = lin & 31;
            float4 v = *(const float4*)&bt[(size_t)(k0 + kk) * 1024 + c0 + c4 * 4];
            *(float4*)&Bs[kk][c4 * 4] = v;
        }
        __syncthreads();
        #pragma unroll 4
        for (int kk = 0; kk < 32; kk++) {
            float4 a0 = *(const float4*)&As[kk][ty * 8];
            float4 a1 = *(const float4*)&As[kk][ty * 8 + 4];
            float4 b0 = *(const float4*)&Bs[kk][tx * 8];
            float4 b1 = *(const float4*)&Bs[kk][tx * 8 + 4];
            const float av[8] = {a0.x, a0.y, a0.z, a0.w, a1.x, a1.y, a1.z, a1.w};
            const float bvv[8] = {b0.x, b0.y, b0.z, b0.w, b1.x, b1.y, b1.z, b1.w};
            #pragma unroll
            for (int i = 0; i < 8; i++)
                #pragma unroll
                for (int j = 0; j < 8; j++)
                    acc[i][j] = fmaf(av[i], bvv[j], acc[i][j]);
        }
        __syncthreads();
    }
    float bias8[8];
    #pragma unroll
    for (int j = 0; j < 8; j++) bias8[j] = bv[c0 + tx * 8 + j];
    #pragma unroll
    for (int i = 0; i < 8; i++) {
        int row = n0 + ty * 8 + i;
        float* cp = C + (size_t)row * 1024 + c0 + tx * 8;
        float4 r0 = make_float4(acc[i][0] + bias8[0], acc[i][1] + bias8[1],
                                acc[i][2] + bias8[2], acc[i][3] + bias8[3]);
        float4 r1 = make_float4(acc[i][4] + bias8[4], acc[i][5] + bias8[5],
                                acc[i][6] + bias8[6], acc[i][7] + bias8[7]);
        *(float4*)cp = r0;
        *(float4*)(cp + 4) = r1;
    }
}

// ---------------------------------------------------------------------------
// Word-level scan, hoisted (v4): h-part recurrence only; x-part (+bias)
// precomputed in pre[n][1024] (n = seq*40 + te, col = dir*512+gate*128+k).
// One WG = (dir, 8-seq group); 400 WGs x 512 thr -> 2x the waves of v3.
// tid: k = tid&127, gp = (tid>>7)&1 (gate pair), hf = tid>>8 (4 seqs each).
// MODE 0: writes h to outp[n*256 + dir*128 + k]; MODE 1: mean over t.
// ---------------------------------------------------------------------------
template <int MODE>
__global__ __launch_bounds__(512) void word_scanH(
    const float* __restrict__ pre,  // [64000][1024]
    const float* __restrict__ wph,  // [2][128][128][4] packed hh
    float* __restrict__ outp) {
    const int T = 40;
    int wg = blockIdx.x;        // 400
    int dir = wg / 200;
    int grp = wg - dir * 200;
    int base = grp * 8;
    int tid = threadIdx.x;
    int k = tid & 127;
    int gp = (tid >> 7) & 1;
    int hf = tid >> 8;
    int sb = hf * 4;

    __shared__ float hs[128][12];      // 8 seqs + pad (48B rows, 16B-aligned)
    __shared__ float pa[2][128][12];

    const float* wp = wph + (size_t)dir * 128 * 512 + k * 4 + gp * 2;

    float c[4], ms[4];
    #pragma unroll
    for (int j = 0; j < 4; j++) { c[j] = 0.f; ms[j] = 0.f; }

    for (int t = 0; t < T; t++) {
        int te = dir ? (T - 1 - t) : t;
        float a0[4], a1[4];
        // load precomputed x-part (+bias)
        #pragma unroll
        for (int j = 0; j < 4; j++) {
            size_t n = (size_t)(base + sb + j) * T + te;
            const float* pr = pre + n * 1024 + (size_t)dir * 512 + gp * 256 + k;
            a0[j] = pr[0];
            a1[j] = pr[128];
        }
        // h-part
        if (t > 0) {
            #pragma unroll 8
            for (int r = 0; r < 128; r++) {
                const float2 w = *(const float2*)(wp + (size_t)r * 512);
                const float4 x0 = *(const float4*)&hs[r][sb];
                const float xv[4] = {x0.x, x0.y, x0.z, x0.w};
                #pragma unroll
                for (int j = 0; j < 4; j++) {
                    a0[j] = fmaf(w.x, xv[j], a0[j]);
                    a1[j] = fmaf(w.y, xv[j], a1[j]);
                }
            }
        }
        // exchange (g,o) preacts; gp0 updates state
        if (gp == 1) {
            #pragma unroll
            for (int j = 0; j < 4; j++) {
                pa[0][k][sb + j] = a0[j];
                pa[1][k][sb + j] = a1[j];
            }
        }
        __syncthreads();
        if (gp == 0) {
            float hv[4];
            #pragma unroll
            for (int j = 0; j < 4; j++) {
                float iv = sigm(a0[j]);
                float fv = sigm(a1[j]);
                float gv = tanhf(pa[0][k][sb + j]);
                float ov = sigm(pa[1][k][sb + j]);
                c[j] = fv * c[j] + iv * gv;
                hv[j] = ov * tanhf(c[j]);
            }
            *(float4*)&hs[k][sb] = make_float4(hv[0], hv[1], hv[2], hv[3]);
            if (MODE == 0) {
                #pragma unroll
                for (int j = 0; j < 4; j++) {
                    outp[(((size_t)(base + sb + j)) * T + te) * 256 +
                         (size_t)dir * 128 + k] = hv[j];
                }
            } else {
                #pragma unroll
                for (int j = 0; j < 4; j++) ms[j] += hv[j];
            }
        }
        __syncthreads();
    }
    if (MODE == 1 && gp == 0) {
        #pragma unroll
        for (int j = 0; j < 4; j++) {
            outp[(size_t)(base + sb + j) * 256 + (size_t)dir * 128 + k] =
                ms[j] * (1.f / T);
        }
    }
}

// ---------------------------------------------------------------------------
// Word-level BiLSTM scan v2 (FUSED x-part) — fallback path if ws too small.
// ---------------------------------------------------------------------------
template <int E, int MODE>
__global__ __launch_bounds__(512) void word_scan2(
    const int* __restrict__ ids, const float* __restrict__ emb,
    const float* __restrict__ xin,
    const float* __restrict__ wpk,   // [2][E+128][128][4]
    const float* __restrict__ bias,  // [2][512]
    float* __restrict__ outp) {
    const int T = 40;
    const int ROWS = E + 128;
    int wg = blockIdx.x;
    int dir = wg / 100;
    int grp = wg - dir * 100;
    int base = grp * 16;
    int tid = threadIdx.x;
    int k = tid & 127;
    int gp = (tid >> 7) & 1;
    int hf = tid >> 8;
    int sb = hf * 8;

    __shared__ float xs[E][20];
    __shared__ float hs[128][20];
    __shared__ float pa[2][128][17];

    const float* wp = wpk + (size_t)dir * ROWS * 512 + k * 4 + gp * 2;
    const float* bb = bias + dir * 512;
    float bi = bb[k], bf_ = bb[128 + k], bg = bb[256 + k], bo = bb[384 + k];

    float c[8], ms[8];
    #pragma unroll
    for (int j = 0; j < 8; j++) { c[j] = 0.f; ms[j] = 0.f; }

    for (int t = 0; t < T; t++) {
        int te = dir ? (T - 1 - t) : t;
        {
            const int NF4 = 16 * (E / 4);
            for (int idx = tid; idx < NF4; idx += 512) {
                int s = idx / (E / 4);
                int e4 = idx - s * (E / 4);
                int seq = base + s;
                float4 v;
                if (MODE == 0) {
                    int id = ids[(size_t)seq * T + te];
                    v = *(const float4*)&emb[(size_t)id * 128 + e4 * 4];
                } else {
                    v = *(const float4*)&xin[((size_t)seq * T + te) * 256 + e4 * 4];
                }
                xs[e4 * 4 + 0][s] = v.x;
                xs[e4 * 4 + 1][s] = v.y;
                xs[e4 * 4 + 2][s] = v.z;
                xs[e4 * 4 + 3][s] = v.w;
            }
        }
        __syncthreads();

        float a0[8], a1[8];
        #pragma unroll
        for (int j = 0; j < 8; j++) { a0[j] = 0.f; a1[j] = 0.f; }

        #pragma unroll 4
        for (int e = 0; e < E; e++) {
            const float2 w = *(const float2*)(wp + (size_t)e * 512);
            const float4 x0 = *(const float4*)&xs[e][sb];
            const float4 x1 = *(const float4*)&xs[e][sb + 4];
            const float xv[8] = {x0.x, x0.y, x0.z, x0.w, x1.x, x1.y, x1.z, x1.w};
            #pragma unroll
            for (int j = 0; j < 8; j++) {
                a0[j] = fmaf(w.x, xv[j], a0[j]);
                a1[j] = fmaf(w.y, xv[j], a1[j]);
            }
        }
        if (t > 0) {
            const float* wh = wp + (size_t)E * 512;
            #pragma unroll 4
            for (int r = 0; r < 128; r++) {
                const float2 w = *(const float2*)(wh + (size_t)r * 512);
                const float4 x0 = *(const float4*)&hs[r][sb];
                const float4 x1 = *(const float4*)&hs[r][sb + 4];
                const float xv[8] = {x0.x, x0.y, x0.z, x0.w, x1.x, x1.y, x1.z, x1.w};
                #pragma unroll
                for (int j = 0; j < 8; j++) {
                    a0[j] = fmaf(w.x, xv[j], a0[j]);
                    a1[j] = fmaf(w.y, xv[j], a1[j]);
                }
            }
        }

        if (gp == 1) {
            #pragma unroll
            for (int j = 0; j < 8; j++) {
                pa[0][k][sb + j] = a0[j];
                pa[1][k][sb + j] = a1[j];
            }
        }
        __syncthreads();
        if (gp == 0) {
            float hv[8];
            #pragma unroll
            for (int j = 0; j < 8; j++) {
                float iv = sigm(a0[j] + bi);
                float fv = sigm(a1[j] + bf_);
                float gv = tanhf(pa[0][k][sb + j] + bg);
                float ov = sigm(pa[1][k][sb + j] + bo);
                c[j] = fv * c[j] + iv * gv;
                hv[j] = ov * tanhf(c[j]);
            }
            *(float4*)&hs[k][sb] = make_float4(hv[0], hv[1], hv[2], hv[3]);
            *(float4*)&hs[k][sb + 4] = make_float4(hv[4], hv[5], hv[6], hv[7]);
            if (MODE == 0) {
                #pragma unroll
                for (int j = 0; j < 8; j++) {
                    outp[(((size_t)(base + sb + j)) * T + te) * 256 +
                         (size_t)dir * 128 + k] = hv[j];
                }
            } else {
                #pragma unroll
                for (int j = 0; j < 8; j++) ms[j] += hv[j];
            }
        }
        __syncthreads();
    }
    if (MODE == 1 && gp == 0) {
        #pragma unroll
        for (int j = 0; j < 8; j++) {
            outp[(size_t)(base + sb + j) * 256 + (size_t)dir * 128 + k] =
                ms[j] * (1.f / T);
        }
    }
}

// ---------------------------------------------------------------------------
// Small fp32 GEMM for doc layers: C[dir][n][g] = A[n][:256] @ Bt[dir][256][512]
// + bias. 64x64 tiles, 256 threads, 4x4 micro-tile.
// ---------------------------------------------------------------------------
__global__ __launch_bounds__(256) void gemm_pre(
    const float* __restrict__ A, const float* __restrict__ Bt,
    const float* __restrict__ bias, float* __restrict__ C) {
    int dir = blockIdx.z;
    const float* B = Bt + (size_t)dir * 256 * 512;
    float* Cp = C + (size_t)dir * 1600 * 512;
    const float* bb = bias + (size_t)dir * 512;
    int n0 = blockIdx.x * 64, g0 = blockIdx.y * 64;
    int tid = threadIdx.x;
    int tx = tid & 15, ty = tid >> 4;
    __shared__ float AsT[32][72];
    __shared__ float Bs[32][72];
    float acc[4][4];
    #pragma unroll
    for (int i = 0; i < 4; i++)
        #pragma unroll
        for (int j = 0; j < 4; j++) acc[i][j] = 0.f;

    for (int k0 = 0; k0 < 256; k0 += 32) {
        #pragma unroll
        for (int it = 0; it < 2; it++) {
            int idx = tid + it * 256;
            int n = idx & 63, e4 = idx >> 6;
            float4 v = *(const float4*)&A[(size_t)(n0 + n) * 256 + k0 + e4 * 4];
            AsT[e4 * 4 + 0][n] = v.x;
            AsT[e4 * 4 + 1][n] = v.y;
            AsT[e4 * 4 + 2][n] = v.z;
            AsT[e4 * 4 + 3][n] = v.w;
        }
        #pragma unroll
        for (int it = 0; it < 2; it++) {
            int idx = tid + it * 256;
            int g4 = idx & 15, e = idx >> 4;
            float4 v = *(const float4*)&B[(size_t)(k0 + e) * 512 + g0 + g4 * 4];
            *(float4*)&Bs[e][g4 * 4] = v;
        }
        __syncthreads();
        #pragma unroll 8
        for (int kk = 0; kk < 32; kk++) {
            float4 a = *(const float4*)&AsT[kk][ty * 4];
            float4 b = *(const float4*)&Bs[kk][tx * 4];
            const float av[4] = {a.x, a.y, a.z, a.w};
            const float bv[4] = {b.x, b.y, b.z, b.w};
            #pragma unroll
            for (int i = 0; i < 4; i++)
                #pragma unroll
                for (int j = 0; j < 4; j++)
                    acc[i][j] = fmaf(av[i], bv[j], acc[i][j]);
        }
        __syncthreads();
    }
    #pragma unroll
    for (int i = 0; i < 4; i++) {
        #pragma unroll
        for (int j = 0; j < 4; j++) {
            Cp[(size_t)(n0 + ty * 4 + i) * 512 + g0 + tx * 4 + j] =
                acc[i][j] + bb[g0 + tx * 4 + j];
        }
    }
}

// ---------------------------------------------------------------------------
// Doc-level BiLSTM scan: recurrent part only. One WG = (dir, 2 batch items).
// ---------------------------------------------------------------------------
__global__ __launch_bounds__(512) void doc_scan2(
    const float* __restrict__ pre,  // [2][32][50][512] (bias included)
    const float* __restrict__ whh,  // [2][128][512]
    float* __restrict__ outp) {     // [1600][256]
    const int S = 50;
    int wg = blockIdx.x;  // 32
    int dir = wg >> 4;
    int b0 = (wg & 15) * 2;
    int g = threadIdx.x;
    int k = g & 127, su = g >> 7;
    __shared__ float hsd[2][128];
    __shared__ float paD[2][512];
    const float* W = whh + (size_t)dir * 128 * 512;
    const float* p0 = pre + ((size_t)dir * 1600 + (size_t)b0 * 50) * 512;
    float cst = 0.f;
    for (int t = 0; t < S; t++) {
        int te = dir ? (S - 1 - t) : t;
        float a0 = p0[(size_t)te * 512 + g];
        float a1 = p0[((size_t)(50 + te)) * 512 + g];
        if (t > 0) {
            #pragma unroll 8
            for (int r = 0; r < 128; r++) {
                float w = W[(size_t)r * 512 + g];
                a0 = fmaf(w, hsd[0][r], a0);
                a1 = fmaf(w, hsd[1][r], a1);
            }
        }
        paD[0][g] = a0;
        paD[1][g] = a1;
        __syncthreads();
        if (g < 256) {
            float pi = paD[su][k], pf = paD[su][128 + k];
            float pg = paD[su][256 + k], po = paD[su][384 + k];
            float iv = sigm(pi), fv = sigm(pf), gv = tanhf(pg), ov = sigm(po);
            cst = fv * cst + iv * gv;
            float hv = ov * tanhf(cst);
            hsd[su][k] = hv;
            outp[((size_t)(b0 + su) * 50 + te) * 256 + (size_t)dir * 128 + k] = hv;
        }
        __syncthreads();
    }
}

// ---------------------------------------------------------------------------
// Head kernel (unchanged).
// ---------------------------------------------------------------------------
__global__ __launch_bounds__(256) void head_kernel(
    const float* __restrict__ outv, const float* __restrict__ content_w,
    const float* __restrict__ content_b, const float* __restrict__ doclT,
    const float* __restrict__ docl_b, const float* __restrict__ salT,
    const float* __restrict__ sal_b, const float* __restrict__ novT,
    const float* __restrict__ nov_b, float* __restrict__ outp) {
    const int S = 50, D = 256;
    int b = blockIdx.x;
    int tid = threadIdx.x;
    __shared__ float oL[50][257];
    __shared__ float mb[256];
    __shared__ float de[256];
    __shared__ float svec[256];
    __shared__ float nvec[256];
    __shared__ float tsum[256];
    __shared__ float predL[64];
    __shared__ float nvL[64];
    __shared__ float red[4][64];

    const float* ob = outv + (size_t)b * S * D;
    for (int i = tid; i < S * D; i += 256) {
        int s = i >> 8, d = i & 255;
        oL[s][d] = ob[i];
    }
    __syncthreads();
    {
        float m = 0;
        for (int s = 0; s < S; s++) m += oL[s][tid];
        mb[tid] = m * (1.f / S);
    }
    __syncthreads();
    {
        float acc = docl_b[tid];
        for (int d = 0; d < D; d++) acc = fmaf(doclT[d * 256 + tid], mb[d], acc);
        de[tid] = tanhf(acc);
    }
    __syncthreads();
    {
        float acc = sal_b[tid];
        for (int d = 0; d < D; d++) acc = fmaf(salT[d * 256 + tid], de[d], acc);
        svec[tid] = acc;
    }
    __syncthreads();
    {
        int s = tid & 63, pw = tid >> 6;
        float ca = 0, sa = 0;
        if (s < S) {
            for (int i = 0; i < 64; i++) {
                int d = pw * 64 + i;
                float ov = oL[s][d];
                ca = fmaf(ov, content_w[d], ca);
                sa = fmaf(ov, svec[d], sa);
            }
        }
        red[pw][s] = ca + sa;
    }
    __syncthreads();
    if (tid < S) {
        predL[tid] = content_b[0] + red[0][tid] + red[1][tid] + red[2][tid] + red[3][tid];
    }
    float summ = 0.f;
    __syncthreads();
    for (int it = 0; it < S; ++it) {
        tsum[tid] = tanhf(summ);
        __syncthreads();
        {
            float acc = nov_b[tid];
            for (int d = 0; d < D; d++) acc = fmaf(novT[d * 256 + tid], tsum[d], acc);
            nvec[tid] = acc;
        }
        __syncthreads();
        {
            int s = tid & 63, pw = tid >> 6;
            float na = 0;
            if (s < S) {
                for (int i = 0; i < 64; i++) {
                    int d = pw * 64 + i;
                    na = fmaf(oL[s][d], nvec[d], na);
                }
            }
            red[pw][s] = na;
        }
        __syncthreads();
        if (tid < S) nvL[tid] = red[0][tid] + red[1][tid] + red[2][tid] + red[3][tid];
        __syncthreads();
        float prob = sigm(predL[it] - nvL[it]);
        summ = fmaf(prob, oL[it][tid], summ);
        __syncthreads();
    }
    if (tid < S) outp[(size_t)b * S + tid] = predL[tid] - nvL[tid];
}

// ---------------------------------------------------------------------------
extern "C" void kernel_launch(void* const* d_in, const int* in_sizes, int n_in,
                              void* d_out, int out_size, void* d_ws, size_t ws_size,
                              hipStream_t stream) {
    const int* ids = (const int*)d_in[0];
    const float* emb = (const float*)d_in[1];
    const float* e_ih0 = (const float*)d_in[2];
    const float* e_hh0 = (const float*)d_in[3];
    const float* e_b0 = (const float*)d_in[4];
    const float* e_ih1 = (const float*)d_in[5];
    const float* e_hh1 = (const float*)d_in[6];
    const float* e_b1 = (const float*)d_in[7];
    const float* d_ih0 = (const float*)d_in[8];
    const float* d_hh0 = (const float*)d_in[9];
    const float* d_b0 = (const float*)d_in[10];
    const float* d_ih1 = (const float*)d_in[11];
    const float* d_hh1 = (const float*)d_in[12];
    const float* d_b1 = (const float*)d_in[13];
    const float* content_w = (const float*)d_in[14];
    const float* content_b = (const float*)d_in[15];
    const float* docl_w = (const float*)d_in[16];
    const float* docl_b = (const float*)d_in[17];
    const float* sal_w = (const float*)d_in[18];
    const float* sal_b = (const float*)d_in[19];
    const float* nov_w = (const float*)d_in[20];
    const float* nov_b = (const float*)d_in[21];
    float* outp = (float*)d_out;

    float* ws = (float*)d_ws;
    size_t off = 0;
    auto alloc = [&](size_t n) { float* p = ws + off; off += n; return p; };
    // --- fallback (fused) word weights ---
    float* wpk0 = alloc((size_t)2 * 256 * 512);
    float* wpk1 = alloc((size_t)2 * 384 * 512);
    // --- hoisted-path word weights ---
    float* wph0 = alloc((size_t)2 * 128 * 512);  // hh-only packs
    float* wph1 = alloc((size_t)2 * 128 * 512);
    float* btw0 = alloc((size_t)128 * 1024);     // W_ih^T for GEMM
    float* btw1 = alloc((size_t)256 * 1024);
    float* bv0 = alloc(1024);
    float* bv1 = alloc(1024);
    // --- doc / head weights ---
    float* bT_d0 = alloc((size_t)2 * 256 * 512);
    float* whh_d0 = alloc((size_t)2 * 128 * 512);
    float* bT_d1 = alloc((size_t)2 * 256 * 512);
    float* whh_d1 = alloc((size_t)2 * 128 * 512);
    float* wT_docl = alloc((size_t)256 * 256);
    float* wT_sal = alloc((size_t)256 * 256);
    float* wT_nov = alloc((size_t)256 * 256);
    // --- activations ---
    float* sent = alloc((size_t)1600 * 256);
    float* pre_d0 = alloc((size_t)2 * 1600 * 512);
    float* d0out = alloc((size_t)1600 * 256);
    float* pre_d1 = alloc((size_t)2 * 1600 * 512);
    float* dout = alloc((size_t)1600 * 256);
    float* h0out = alloc((size_t)64000 * 256);
    size_t need_fallback = off * 4;
    float* pre = alloc((size_t)64000 * 1024);    // 262 MB, hoisted path only
    size_t need_hoist = off * 4;
    (void)in_sizes; (void)n_in; (void)out_size; (void)need_fallback;

    bool hoist = ws_size >= need_hoist;

    dim3 tb(32, 8);
    // --- doc/head weight prep (both paths) ---
    transpose_k<<<dim3(256 / 32, 512 / 32, 2), tb, 0, stream>>>(d_ih0, bT_d0, 512, 256);
    transpose_k<<<dim3(128 / 32, 512 / 32, 2), tb, 0, stream>>>(d_hh0, whh_d0, 512, 128);
    transpose_k<<<dim3(256 / 32, 512 / 32, 2), tb, 0, stream>>>(d_ih1, bT_d1, 512, 256);
    transpose_k<<<dim3(128 / 32, 512 / 32, 2), tb, 0, stream>>>(d_hh1, whh_d1, 512, 128);
    transpose_k<<<dim3(256 / 32, 256 / 32, 1), tb, 0, stream>>>(docl_w, wT_docl, 256, 256);
    transpose_k<<<dim3(256 / 32, 256 / 32, 1), tb, 0, stream>>>(sal_w, wT_sal, 256, 256);
    transpose_k<<<dim3(256 / 32, 256 / 32, 1), tb, 0, stream>>>(nov_w, wT_nov, 256, 256);

    if (hoist) {
        // hh-only packs (E=0 -> ih pointer unused)
        pack_w<<<256, 256, 0, stream>>>(e_hh0, e_hh0, wph0, 0);
        pack_w<<<256, 256, 0, stream>>>(e_hh1, e_hh1, wph1, 0);
        pack_bt<<<256, 256, 0, stream>>>(e_ih0, e_b0, btw0, bv0, 128);
        pack_bt<<<512, 256, 0, stream>>>(e_ih1, e_b1, btw1, bv1, 256);

        // word L0: x-part GEMM (emb gather fused) + h-recurrence
        gemm_x<128, 1><<<dim3(500, 8), 256, 0, stream>>>(nullptr, ids, emb,
                                                         btw0, bv0, pre);
        word_scanH<0><<<400, 512, 0, stream>>>(pre, wph0, h0out);
        // word L1
        gemm_x<256, 0><<<dim3(500, 8), 256, 0, stream>>>(h0out, nullptr, nullptr,
                                                         btw1, bv1, pre);
        word_scanH<1><<<400, 512, 0, stream>>>(pre, wph1, sent);
    } else {
        // fallback: fused scans (v2)
        pack_w<<<1024, 256, 0, stream>>>(e_ih0, e_hh0, wpk0, 128);
        pack_w<<<1536, 256, 0, stream>>>(e_ih1, e_hh1, wpk1, 256);
        word_scan2<128, 0><<<200, 512, 0, stream>>>(ids, emb, nullptr, wpk0, e_b0, h0out);
        word_scan2<256, 1><<<200, 512, 0, stream>>>(nullptr, nullptr, h0out, wpk1,
                                                    e_b1, sent);
    }

    // doc-level BiLSTM layers
    gemm_pre<<<dim3(25, 8, 2), 256, 0, stream>>>(sent, bT_d0, d_b0, pre_d0);
    doc_scan2<<<32, 512, 0, stream>>>(pre_d0, whh_d0, d0out);
    gemm_pre<<<dim3(25, 8, 2), 256, 0, stream>>>(d0out, bT_d1, d_b1, pre_d1);
    doc_scan2<<<32, 512, 0, stream>>>(pre_d1, whh_d1, dout);

    // head
    head_kernel<<<32, 256, 0, stream>>>(dout, content_w, content_b, wT_docl, docl_b,
                                        wT_sal, sal_b, wT_nov, nov_b, outp);
}